// Round 1
// 4127.419 us; speedup vs baseline: 1.5696x; 1.5696x over previous
//
#include <hip/hip_runtime.h>

typedef _Float16 f16;
typedef _Float16 f16x8 __attribute__((ext_vector_type(8)));
typedef float f32x4 __attribute__((ext_vector_type(4)));
typedef unsigned short ushort_t;

// ---------------------------------------------------------------------------
// PoseConvLSTM via implicit-GEMM MFMA (split-fp16 hi/lo, 3-MFMA per product).
//
// State buffers (ws, ushort f16 bits), padded-transposed layout [66][66][C]:
//   in1[parity]: C=48: c0-2 = x[t], c3-34 = h1prev, c35-47 = 0
//   in2[parity]: C=96: c0-31 = h1[t], c32-95 = h2prev
// Weights packed at init into MFMA A-fragment order (hi/lo f16).
//
// Round 1 changes (latency-hiding package):
//  - L1: FULL weight-slice register preload (36 x b128, issued before LDS
//    staging so they complete under the staging barrier) -> K-loop has zero
//    vmcnt stalls.
//  - L2: 8-deep rolling A-fragment register pipeline (7-step prefetch
//    distance ~= 1000 cyc cover), K-loop fully unrolled (static ring indices).
//  - __launch_bounds__(256,1): grid==256 blocks == 1 block/CU, so VGPRs are
//    free up to 512; let the allocator keep the pipeline in registers.
//  - fast tanh/sigmoid via v_exp_f32 + v_rcp_f32 (error ~1e-7, negligible
//    vs split-f16 GEMM error).
//
// d_out (floats): pose[768] | h1[131072] | c1[131072] | h2[262144] | c2[262144]
// ---------------------------------------------------------------------------

#define IN1SZ 209088   // 66*66*48
#define IN2SZ 418176   // 66*66*96
#define WP1OFF 2509056            // ushort offset of wp1 (after 4*IN1SZ + 4*IN2SZ)
#define WP1SZ 147456              // 2mb*18s*4mt*2hl*512
#define WP2OFF (WP1OFF + WP1SZ)
#define WP2SZ 442368              // 2mb*27s*8mt*2hl*512

__device__ __forceinline__ float sigm(float x) {
  return __builtin_amdgcn_rcpf(1.0f + __expf(-x));
}
__device__ __forceinline__ float tanh_fast(float x) {
  float xc = fminf(fmaxf(x, -10.f), 10.f);
  float e = __expf(2.f * xc);
  return (e - 1.f) * __builtin_amdgcn_rcpf(e + 1.f);
}
__device__ __forceinline__ ushort_t f2u(f16 v) { return __builtin_bit_cast(ushort_t, v); }
__device__ __forceinline__ f16x8 u2f(uint4 v) { return __builtin_bit_cast(f16x8, v); }

// ---- init: pack weights into fragment order, pose=fc_b, stage x[0] ----
__global__ __launch_bounds__(256) void pack_kernel(const float* __restrict__ w1,
                                                   const float* __restrict__ w2,
                                                   const float* __restrict__ fcb,
                                                   const float* __restrict__ x0,
                                                   float* __restrict__ pose,
                                                   ushort_t* __restrict__ wp1,
                                                   ushort_t* __restrict__ wp2,
                                                   ushort_t* __restrict__ in1hi0,
                                                   ushort_t* __restrict__ in1lo0) {
  int i = blockIdx.x * 256 + threadIdx.x;
  if (i < 55296) {  // wp2: thread per (f, hl, lane), 8 elems each
    int lane = i & 63;
    int r0 = i >> 6;        // [0, 864)
    int hl = r0 & 1;
    int f = r0 >> 1;        // [0, 432) = (mb*27+s)*8+mt
    int mt = f & 7;
    int sm = f >> 3;        // [0,54)
    int s = sm % 27, mb = sm / 27;
    int m = mt * 16 + (lane & 15);
    int rg = mb * 128 + m;
    int h = rg >> 2, G = rg & 3;
    int orow = G * 64 + h;
    int tap = s / 3, cb = (s % 3) * 32;
    int cq = cb + (lane >> 4) * 8;
    for (int j = 0; j < 8; ++j) {
      float v = w2[(orow * 96 + cq + j) * 9 + tap];
      f16 vh = (f16)v;
      f16 vl = (f16)(v - (float)vh);
      wp2[(f * 2 + hl) * 512 + lane * 8 + j] = f2u(hl ? vl : vh);
    }
    return;
  }
  i -= 55296;
  if (i < 18432) {  // wp1
    int lane = i & 63;
    int r0 = i >> 6;        // [0,288)
    int hl = r0 & 1;
    int f = r0 >> 1;        // [0,144) = (mb*18+s)*4+mt
    int mt = f & 3;
    int sm = f >> 2;        // [0,36)
    int s = sm % 18, mb = sm / 18;
    int m = mt * 16 + (lane & 15);
    int rg = mb * 64 + m;
    int h = rg >> 2, G = rg & 3;
    int orow = G * 32 + h;
    int tap = s >> 1, cb = (s & 1) * 32;
    int cq = cb + (lane >> 4) * 8;
    for (int j = 0; j < 8; ++j) {
      int c = cq + j;
      float v = (c < 35) ? w1[(orow * 35 + c) * 9 + tap] : 0.f;
      f16 vh = (f16)v;
      f16 vl = (f16)(v - (float)vh);
      wp1[(f * 2 + hl) * 512 + lane * 8 + j] = f2u(hl ? vl : vh);
    }
    return;
  }
  i -= 18432;
  if (i < 768) { pose[i] = fcb[i % 6]; return; }
  i -= 768;
  if (i < 12288) {  // x[0] -> in1[0] c0-2
    int c = i >> 12, pix = i & 4095;
    int y = pix >> 6, x = pix & 63;
    float v = x0[i];
    f16 vh = (f16)v;
    f16 vl = (f16)(v - (float)vh);
    int pidx = ((y + 1) * 66 + (x + 1)) * 48 + c;
    in1hi0[pidx] = f2u(vh);
    in1lo0[pidx] = f2u(vl);
  }
}

// ---- one ConvLSTM step for one layer ----
// grid 256 = 2 M-blocks x 128 pixel tiles (4y x 8x); block 256 = 4 waves.
template <int LAYER>
__global__ __launch_bounds__(256, 1) void conv_step(
    const ushort_t* __restrict__ bhi, const ushort_t* __restrict__ blo,  // input buffer
    const ushort_t* __restrict__ wp, const float* __restrict__ bias,
    float* __restrict__ cst, float* __restrict__ hout,              // fp32 c (in-place), h
    ushort_t* __restrict__ d1hi, ushort_t* __restrict__ d1lo,       // primary padded dest
    ushort_t* __restrict__ d2hi, ushort_t* __restrict__ d2lo,       // secondary (L1 only)
    const float* __restrict__ fcw, float* __restrict__ pose_t,      // L2 only
    const float* __restrict__ xn,                                   // L2 only: x[t+1]
    ushort_t* __restrict__ xdhi, ushort_t* __restrict__ xdlo) {     // L2 only: in1 next
  constexpr int CS = (LAYER == 1) ? 72 : 104;   // LDS c-stride (bank-conflict pad)
  constexpr int NC32 = (LAYER == 1) ? 2 : 3;    // 32-channel chunks
  constexpr int NS = 9 * NC32;                  // k32 steps
  constexpr int MT = (LAYER == 1) ? 4 : 8;      // 16-row m-tiles per block
  constexpr int MTPW = (LAYER == 1) ? 1 : 2;    // m-tiles per wave
  constexpr int ROWS = MT * 16;
  constexpr int H = (LAYER == 1) ? 32 : 64;
  constexpr int ZS = 33;                        // z LDS stride (pad)
  constexpr int D1S = (LAYER == 1) ? 48 : 96;
  constexpr int D1O = (LAYER == 1) ? 3 : 32;
  // A-fragment register pipeline depth: L1 holds the FULL slice (18 steps,
  // 144 VGPRs); L2 uses an 8-slot ring (7-step prefetch distance, 128 VGPRs).
  constexpr int DEPTH = (LAYER == 1) ? NS : 8;
  constexpr int PRE = (DEPTH < NS) ? (DEPTH - 1) : NS;

  __shared__ __align__(16) ushort_t Bh[60 * CS];
  __shared__ __align__(16) ushort_t Bl[60 * CS];
  __shared__ float zs[ROWS * ZS];
  __shared__ float red[4][6];

  const int tid = threadIdx.x;
  const int lane = tid & 63;
  const int w = tid >> 6;
  const int mb = blockIdx.x & 1;
  const int ntile = blockIdx.x >> 1;
  const int Y0 = (ntile >> 3) * 4;
  const int X0 = (ntile & 7) * 8;

  // ---- A-frag register pipeline: issue loads EARLY (overlap with staging) ----
  const ushort_t* aptr[MTPW];
#pragma unroll
  for (int m = 0; m < MTPW; ++m) {
    int f = (mb * NS) * MT + (w * MTPW + m);
    aptr[m] = wp + f * 1024 + lane * 8;
  }
  uint4 A[DEPTH][MTPW][2];
  auto loada = [&](int s) {
#pragma unroll
    for (int m = 0; m < MTPW; ++m) {
      const ushort_t* p = aptr[m] + (size_t)s * (MT * 1024);
      A[s % DEPTH][m][0] = *(const uint4*)(p);
      A[s % DEPTH][m][1] = *(const uint4*)(p + 512);
    }
  };
#pragma unroll
  for (int s = 0; s < PRE; ++s) loada(s);

  // ---- stage halo slab [6y][10x][C] into LDS (already-split f16) ----
  if (LAYER == 2) {
    for (int i = tid; i < 720; i += 256) {
      int hy = i / 120, rem = i % 120;
      int hx = rem / 12, c8 = (rem % 12) * 8;
      int src = ((Y0 + hy) * 66 + X0 + hx) * 96 + c8;
      int dst = (hy * 10 + hx) * CS + c8;
      *(uint4*)(&Bh[dst]) = *(const uint4*)(&bhi[src]);
      *(uint4*)(&Bl[dst]) = *(const uint4*)(&blo[src]);
    }
  } else {
    for (int i = tid; i < 360; i += 256) {
      int hy = i / 60, rem = i % 60;
      int hx = rem / 6, c8 = (rem % 6) * 8;
      int src = ((Y0 + hy) * 66 + X0 + hx) * 48 + c8;
      int dst = (hy * 10 + hx) * CS + c8;
      *(uint4*)(&Bh[dst]) = *(const uint4*)(&bhi[src]);
      *(uint4*)(&Bl[dst]) = *(const uint4*)(&blo[src]);
    }
    for (int i = tid; i < 120; i += 256) {  // zero-pad c 48..63 (read by frags)
      int hp = i >> 1;
      int dst = hp * CS + 48 + (i & 1) * 8;
      *(uint4*)(&Bh[dst]) = uint4{0, 0, 0, 0};
      *(uint4*)(&Bl[dst]) = uint4{0, 0, 0, 0};
    }
  }
  __syncthreads();

  // ---- K-loop: A frags from registers (pipelined), B frags from LDS ----
  const int n = lane & 15;
  const int q = lane >> 4;
  const int py = n >> 3, px = n & 7;

  f32x4 acc[MTPW][2];
#pragma unroll
  for (int m = 0; m < MTPW; ++m)
#pragma unroll
    for (int nt = 0; nt < 2; ++nt) acc[m][nt] = f32x4{0.f, 0.f, 0.f, 0.f};

#pragma unroll
  for (int s = 0; s < NS; ++s) {
    // rolling prefetch: writes ring slot consumed LAST iteration (WAR-bounded)
    if (s + PRE < NS) loada(s + PRE);
    const int tap = s / NC32, cc = s % NC32;
    const int ty = tap / 3, tx = tap % 3;
    const int coff = cc * 32 + q * 8;
    f16x8 bfh[2], bfl[2];
#pragma unroll
    for (int nt = 0; nt < 2; ++nt) {
      int hp = (py + nt * 2 + ty) * 10 + (px + tx);
      int a = hp * CS + coff;
      bfh[nt] = u2f(*(const uint4*)(&Bh[a]));
      bfl[nt] = u2f(*(const uint4*)(&Bl[a]));
    }
#pragma unroll
    for (int m = 0; m < MTPW; ++m) {
      f16x8 ah = u2f(A[s % DEPTH][m][0]);
      f16x8 al = u2f(A[s % DEPTH][m][1]);
#pragma unroll
      for (int nt = 0; nt < 2; ++nt) {
        acc[m][nt] = __builtin_amdgcn_mfma_f32_16x16x32_f16(ah, bfh[nt], acc[m][nt], 0, 0, 0);
        acc[m][nt] = __builtin_amdgcn_mfma_f32_16x16x32_f16(ah, bfl[nt], acc[m][nt], 0, 0, 0);
        acc[m][nt] = __builtin_amdgcn_mfma_f32_16x16x32_f16(al, bfh[nt], acc[m][nt], 0, 0, 0);
      }
    }
  }

  // ---- z exchange through LDS ----
#pragma unroll
  for (int m = 0; m < MTPW; ++m) {
    int mt = w * MTPW + m;
#pragma unroll
    for (int nt = 0; nt < 2; ++nt)
#pragma unroll
      for (int i = 0; i < 4; ++i) zs[(mt * 16 + q * 4 + i) * ZS + nt * 16 + n] = acc[m][nt][i];
  }
  __syncthreads();

  // ---- LSTM cell + state writes (+ FC fuse for L2) ----
  constexpr int NCELL = (MT * 4 * 32) / 256;  // cells per thread (L2: 4, L1: 2)
  float p6[6] = {0, 0, 0, 0, 0, 0};
#pragma unroll
  for (int i = 0; i < NCELL; ++i) {
    int idx = i * 256 + tid;
    int ch = idx >> 5, pI = idx & 31;
    float zi = zs[(ch * 4 + 0) * ZS + pI];
    float zf = zs[(ch * 4 + 1) * ZS + pI];
    float zo = zs[(ch * 4 + 2) * ZS + pI];
    float zg = zs[(ch * 4 + 3) * ZS + pI];
    int hg = mb * (MT * 4) + ch;
    zi += bias[0 * H + hg];
    zf += bias[1 * H + hg];
    zo += bias[2 * H + hg];
    zg += bias[3 * H + hg];
    int y = Y0 + (pI >> 3), x = X0 + (pI & 7);
    int cidx = hg * 4096 + y * 64 + x;
    float cold = cst[cidx];
    float cn = sigm(zf) * cold + sigm(zi) * tanh_fast(zg);
    float hn = sigm(zo) * tanh_fast(cn);
    cst[cidx] = cn;
    hout[cidx] = hn;
    f16 hh = (f16)hn;
    f16 hl = (f16)(hn - (float)hh);
    int pidx = (y + 1) * 66 + (x + 1);
    d1hi[pidx * D1S + D1O + hg] = f2u(hh);
    d1lo[pidx * D1S + D1O + hg] = f2u(hl);
    if (LAYER == 1) {
      d2hi[pidx * 96 + hg] = f2u(hh);
      d2lo[pidx * 96 + hg] = f2u(hl);
    } else {
#pragma unroll
      for (int j = 0; j < 6; ++j) p6[j] += hn * fcw[j * 262144 + cidx];
    }
  }

  if (LAYER == 2) {
#pragma unroll
    for (int j = 0; j < 6; ++j)
#pragma unroll
      for (int off = 32; off > 0; off >>= 1) p6[j] += __shfl_xor(p6[j], off, 64);
    if (lane == 0)
#pragma unroll
      for (int j = 0; j < 6; ++j) red[w][j] = p6[j];
    __syncthreads();
    if (tid < 6) atomicAdd(pose_t + tid, red[0][tid] + red[1][tid] + red[2][tid] + red[3][tid]);
    // stage x[t+1] into in1 next-parity (c0-2)
    if (mb == 0 && tid < 32) {
      int y = Y0 + (tid >> 3), x = X0 + (tid & 7);
      int pidx = (y + 1) * 66 + (x + 1);
#pragma unroll
      for (int c = 0; c < 3; ++c) {
        float v = xn[c * 4096 + y * 64 + x];
        f16 vh = (f16)v;
        f16 vl = (f16)(v - (float)vh);
        xdhi[pidx * 48 + c] = f2u(vh);
        xdlo[pidx * 48 + c] = f2u(vl);
      }
    }
  }
}

extern "C" void kernel_launch(void* const* d_in, const int* in_sizes, int n_in, void* d_out,
                              int out_size, void* d_ws, size_t ws_size, hipStream_t stream) {
  const float* input = (const float*)d_in[0];
  const float* w1 = (const float*)d_in[1];
  const float* b1 = (const float*)d_in[2];
  const float* w2 = (const float*)d_in[3];
  const float* b2 = (const float*)d_in[4];
  const float* fcw = (const float*)d_in[5];
  const float* fcb = (const float*)d_in[6];

  float* out = (float*)d_out;
  float* pose = out;
  float* h1o = out + 768;
  float* c1o = h1o + 131072;
  float* h2o = c1o + 131072;
  float* c2o = h2o + 262144;

  ushort_t* ws = (ushort_t*)d_ws;
  ushort_t* in1hi[2] = {ws, ws + IN1SZ};
  ushort_t* in1lo[2] = {ws + 2 * IN1SZ, ws + 3 * IN1SZ};
  ushort_t* i2base = ws + 4 * IN1SZ;
  ushort_t* in2hi[2] = {i2base, i2base + IN2SZ};
  ushort_t* in2lo[2] = {i2base + 2 * IN2SZ, i2base + 3 * IN2SZ};
  ushort_t* wp1 = ws + WP1OFF;
  ushort_t* wp2 = ws + WP2OFF;

  // zero state buffers (t=0 h-states + padded borders + c-pads), c/h fp32 states
  hipMemsetAsync(ws, 0, (size_t)WP1OFF * 2, stream);
  hipMemsetAsync(out + 768, 0, (size_t)786432 * 4, stream);
  pack_kernel<<<339, 256, 0, stream>>>(w1, w2, fcb, input, pose, wp1, wp2, in1hi[0], in1lo[0]);

  for (int t = 0; t < 128; ++t) {
    int p = t & 1, pn = p ^ 1;
    conv_step<1><<<256, 256, 0, stream>>>(in1hi[p], in1lo[p], wp1, b1, c1o, h1o,
                                          in1hi[pn], in1lo[pn],  // h1 -> in1 next @c3
                                          in2hi[p], in2lo[p],    // h1 -> in2 cur  @c0
                                          nullptr, nullptr, nullptr, nullptr, nullptr);
    int tn = (t + 1 < 128) ? t + 1 : 127;
    conv_step<2><<<256, 256, 0, stream>>>(in2hi[p], in2lo[p], wp2, b2, c2o, h2o,
                                          in2hi[pn], in2lo[pn],  // h2 -> in2 next @c32
                                          nullptr, nullptr,
                                          fcw, pose + t * 6,
                                          input + (size_t)tn * 12288, in1hi[pn], in1lo[pn]);
  }
}

// Round 3
// 3557.613 us; speedup vs baseline: 1.8211x; 1.1602x over previous
//
#include <hip/hip_runtime.h>

typedef _Float16 f16;
typedef _Float16 f16x8 __attribute__((ext_vector_type(8)));
typedef float f32x4 __attribute__((ext_vector_type(4)));
typedef unsigned short ushort_t;

// ---------------------------------------------------------------------------
// PoseConvLSTM via implicit-GEMM MFMA (split-fp16 hi/lo, 3-MFMA per product).
//
// Round 3: temporal-skew fusion (round 2) + XCD false-sharing fix.
// Kernel K_t computes L1[t] (blocks 0-255) and L2[t-1] (blocks 256-511)
// concurrently. Round 2 failed post-timing: L1-role and L2-role blocks wrote
// disjoint CHANNELS of the same in2 pixel record -> same 128B cache line
// dirty in two non-coherent XCD L2s -> lost updates on warm-cache calls.
// Fix: in2 split into two 128B-aligned buffers, each written by ONE role:
//   in2a[parity]: [66][66][32]  h1[t]   (written by L1 role only)
//   in2b[parity]: [66][66][64]  h2[t-1] (written by L2 role only)
// L2 staging reads both. No cross-role cache-line sharing remains anywhere
// (d_out region boundaries are 128B-aligned; pose atomics are device-scope).
//
// d_out (floats): pose[768] | h1[131072] | c1[131072] | h2[262144] | c2[262144]
// ---------------------------------------------------------------------------

#define IN1SZ 209088    // 66*66*48
#define IN2ASZ 139392   // 66*66*32
#define IN2BSZ 278784   // 66*66*64
#define WP1OFF 2509056  // ushort offset of wp1 (4*IN1SZ + 4*IN2ASZ + 4*IN2BSZ)
#define WP1SZ 147456    // 2mb*18s*4mt*2hl*512
#define WP2OFF (WP1OFF + WP1SZ)
#define WP2SZ 442368    // 2mb*27s*8mt*2hl*512

__device__ __forceinline__ float sigm(float x) {
  return __builtin_amdgcn_rcpf(1.0f + __expf(-x));
}
__device__ __forceinline__ float tanh_fast(float x) {
  float xc = fminf(fmaxf(x, -10.f), 10.f);
  float e = __expf(2.f * xc);
  return (e - 1.f) * __builtin_amdgcn_rcpf(e + 1.f);
}
__device__ __forceinline__ ushort_t f2u(f16 v) { return __builtin_bit_cast(ushort_t, v); }
__device__ __forceinline__ f16x8 u2f(uint4 v) { return __builtin_bit_cast(f16x8, v); }

// ---- init: pack weights into fragment order, pose=fc_b, stage x[0] ----
__global__ __launch_bounds__(256) void pack_kernel(const float* __restrict__ w1,
                                                   const float* __restrict__ w2,
                                                   const float* __restrict__ fcb,
                                                   const float* __restrict__ x0,
                                                   float* __restrict__ pose,
                                                   ushort_t* __restrict__ wp1,
                                                   ushort_t* __restrict__ wp2,
                                                   ushort_t* __restrict__ in1hi0,
                                                   ushort_t* __restrict__ in1lo0) {
  int i = blockIdx.x * 256 + threadIdx.x;
  if (i < 55296) {  // wp2: thread per (f, hl, lane), 8 elems each
    int lane = i & 63;
    int r0 = i >> 6;        // [0, 864)
    int hl = r0 & 1;
    int f = r0 >> 1;        // [0, 432) = (mb*27+s)*8+mt
    int mt = f & 7;
    int sm = f >> 3;        // [0,54)
    int s = sm % 27, mb = sm / 27;
    int m = mt * 16 + (lane & 15);
    int rg = mb * 128 + m;
    int h = rg >> 2, G = rg & 3;
    int orow = G * 64 + h;
    int tap = s / 3, cb = (s % 3) * 32;
    int cq = cb + (lane >> 4) * 8;
    for (int j = 0; j < 8; ++j) {
      float v = w2[(orow * 96 + cq + j) * 9 + tap];
      f16 vh = (f16)v;
      f16 vl = (f16)(v - (float)vh);
      wp2[(f * 2 + hl) * 512 + lane * 8 + j] = f2u(hl ? vl : vh);
    }
    return;
  }
  i -= 55296;
  if (i < 18432) {  // wp1
    int lane = i & 63;
    int r0 = i >> 6;        // [0,288)
    int hl = r0 & 1;
    int f = r0 >> 1;        // [0,144) = (mb*18+s)*4+mt
    int mt = f & 3;
    int sm = f >> 2;        // [0,36)
    int s = sm % 18, mb = sm / 18;
    int m = mt * 16 + (lane & 15);
    int rg = mb * 64 + m;
    int h = rg >> 2, G = rg & 3;
    int orow = G * 32 + h;
    int tap = s >> 1, cb = (s & 1) * 32;
    int cq = cb + (lane >> 4) * 8;
    for (int j = 0; j < 8; ++j) {
      int c = cq + j;
      float v = (c < 35) ? w1[(orow * 35 + c) * 9 + tap] : 0.f;
      f16 vh = (f16)v;
      f16 vl = (f16)(v - (float)vh);
      wp1[(f * 2 + hl) * 512 + lane * 8 + j] = f2u(hl ? vl : vh);
    }
    return;
  }
  i -= 18432;
  if (i < 768) { pose[i] = fcb[i % 6]; return; }
  i -= 768;
  if (i < 12288) {  // x[0] -> in1[0] c0-2
    int c = i >> 12, pix = i & 4095;
    int y = pix >> 6, x = pix & 63;
    float v = x0[i];
    f16 vh = (f16)v;
    f16 vl = (f16)(v - (float)vh);
    int pidx = ((y + 1) * 66 + (x + 1)) * 48 + c;
    in1hi0[pidx] = f2u(vh);
    in1lo0[pidx] = f2u(vl);
  }
}

// ---- one ConvLSTM step for one layer (device body) ----
// bid in [0,256) = 2 M-blocks x 128 pixel tiles (4y x 8x); block 256 = 4 waves.
// L1: input = bhi/blo (in1, 48ch). Writes d1 = in1-next (h1@c3 + x@c0),
//     d2 = in2a (h1, 32ch stride).
// L2: input = bhi/blo (in2a, 32ch) + b2hi/b2lo (in2b, 64ch). Writes d1 = in2b.
template <int LAYER>
__device__ __forceinline__ void conv_body(
    int bid,
    const ushort_t* __restrict__ bhi, const ushort_t* __restrict__ blo,
    const ushort_t* __restrict__ b2hi, const ushort_t* __restrict__ b2lo,
    const ushort_t* __restrict__ wp, const float* __restrict__ bias,
    float* __restrict__ cst, float* __restrict__ hout,              // fp32 c (in-place), h
    ushort_t* __restrict__ d1hi, ushort_t* __restrict__ d1lo,       // primary dest
    ushort_t* __restrict__ d2hi, ushort_t* __restrict__ d2lo,       // secondary (L1 only)
    const float* __restrict__ fcw, float* __restrict__ pose_t,      // L2 only
    const float* __restrict__ xn,                                   // L1 only: x[t+1]
    ushort_t* Bh, ushort_t* Bl, float* zs, float (*red)[6]) {
  constexpr int CS = (LAYER == 1) ? 72 : 104;   // LDS c-stride (bank-conflict pad)
  constexpr int NC32 = (LAYER == 1) ? 2 : 3;    // 32-channel chunks
  constexpr int NS = 9 * NC32;                  // k32 steps
  constexpr int MT = (LAYER == 1) ? 4 : 8;      // 16-row m-tiles per block
  constexpr int MTPW = (LAYER == 1) ? 1 : 2;    // m-tiles per wave
  constexpr int H = (LAYER == 1) ? 32 : 64;
  constexpr int ZS = 33;                        // z LDS stride (pad)
  constexpr int D1S = (LAYER == 1) ? 48 : 64;   // primary dest c-stride
  constexpr int D1O = (LAYER == 1) ? 3 : 0;     // primary dest c-offset
  constexpr int DEPTH = 6;                      // A-frag register ring
  constexpr int PRE = DEPTH - 1;

  const int tid = threadIdx.x;
  const int lane = tid & 63;
  const int w = tid >> 6;
  const int mb = bid & 1;
  const int ntile = bid >> 1;
  const int Y0 = (ntile >> 3) * 4;
  const int X0 = (ntile & 7) * 8;

  // ---- A-frag register ring: issue loads EARLY (overlap with staging) ----
  const ushort_t* aptr[MTPW];
#pragma unroll
  for (int m = 0; m < MTPW; ++m) {
    int f = (mb * NS) * MT + (w * MTPW + m);
    aptr[m] = wp + f * 1024 + lane * 8;
  }
  uint4 A[DEPTH][MTPW][2];
  auto loada = [&](int s) {
#pragma unroll
    for (int m = 0; m < MTPW; ++m) {
      const ushort_t* p = aptr[m] + (size_t)s * (MT * 1024);
      A[s % DEPTH][m][0] = *(const uint4*)(p);
      A[s % DEPTH][m][1] = *(const uint4*)(p + 512);
    }
  };
#pragma unroll
  for (int s = 0; s < PRE; ++s) loada(s);

  // ---- stage halo slab [6y][10x][C] into LDS (already-split f16) ----
  if (LAYER == 2) {
    for (int i = tid; i < 720; i += 256) {
      int hy = i / 120, rem = i % 120;
      int hx = rem / 12, c8 = rem % 12;
      int pos = (Y0 + hy) * 66 + X0 + hx;
      int dst = (hy * 10 + hx) * CS + c8 * 8;
      if (c8 < 4) {  // c0-31 from in2a (h1)
        int src = pos * 32 + c8 * 8;
        *(uint4*)(&Bh[dst]) = *(const uint4*)(&bhi[src]);
        *(uint4*)(&Bl[dst]) = *(const uint4*)(&blo[src]);
      } else {       // c32-95 from in2b (h2)
        int src = pos * 64 + (c8 - 4) * 8;
        *(uint4*)(&Bh[dst]) = *(const uint4*)(&b2hi[src]);
        *(uint4*)(&Bl[dst]) = *(const uint4*)(&b2lo[src]);
      }
    }
  } else {
    for (int i = tid; i < 360; i += 256) {
      int hy = i / 60, rem = i % 60;
      int hx = rem / 6, c8 = (rem % 6) * 8;
      int src = ((Y0 + hy) * 66 + X0 + hx) * 48 + c8;
      int dst = (hy * 10 + hx) * CS + c8;
      *(uint4*)(&Bh[dst]) = *(const uint4*)(&bhi[src]);
      *(uint4*)(&Bl[dst]) = *(const uint4*)(&blo[src]);
    }
    for (int i = tid; i < 120; i += 256) {  // zero-pad c 48..63 (read by frags)
      int hp = i >> 1;
      int dst = hp * CS + 48 + (i & 1) * 8;
      *(uint4*)(&Bh[dst]) = uint4{0, 0, 0, 0};
      *(uint4*)(&Bl[dst]) = uint4{0, 0, 0, 0};
    }
  }
  __syncthreads();

  // ---- K-loop: A frags from registers (ring-prefetched), B frags from LDS ----
  const int n = lane & 15;
  const int q = lane >> 4;
  const int py = n >> 3, px = n & 7;

  f32x4 acc[MTPW][2];
#pragma unroll
  for (int m = 0; m < MTPW; ++m)
#pragma unroll
    for (int nt = 0; nt < 2; ++nt) acc[m][nt] = f32x4{0.f, 0.f, 0.f, 0.f};

#pragma unroll
  for (int s = 0; s < NS; ++s) {
    // rolling prefetch: writes ring slot consumed LAST iteration (WAR-bounded)
    if (s + PRE < NS) loada(s + PRE);
    const int tap = s / NC32, cc = s % NC32;
    const int ty = tap / 3, tx = tap % 3;
    const int coff = cc * 32 + q * 8;
    f16x8 bfh[2], bfl[2];
#pragma unroll
    for (int nt = 0; nt < 2; ++nt) {
      int hp = (py + nt * 2 + ty) * 10 + (px + tx);
      int a = hp * CS + coff;
      bfh[nt] = u2f(*(const uint4*)(&Bh[a]));
      bfl[nt] = u2f(*(const uint4*)(&Bl[a]));
    }
#pragma unroll
    for (int m = 0; m < MTPW; ++m) {
      f16x8 ah = u2f(A[s % DEPTH][m][0]);
      f16x8 al = u2f(A[s % DEPTH][m][1]);
#pragma unroll
      for (int nt = 0; nt < 2; ++nt) {
        acc[m][nt] = __builtin_amdgcn_mfma_f32_16x16x32_f16(ah, bfh[nt], acc[m][nt], 0, 0, 0);
        acc[m][nt] = __builtin_amdgcn_mfma_f32_16x16x32_f16(ah, bfl[nt], acc[m][nt], 0, 0, 0);
        acc[m][nt] = __builtin_amdgcn_mfma_f32_16x16x32_f16(al, bfh[nt], acc[m][nt], 0, 0, 0);
      }
    }
  }

  // ---- z exchange through LDS ----
#pragma unroll
  for (int m = 0; m < MTPW; ++m) {
    int mt = w * MTPW + m;
#pragma unroll
    for (int nt = 0; nt < 2; ++nt)
#pragma unroll
      for (int i = 0; i < 4; ++i) zs[(mt * 16 + q * 4 + i) * ZS + nt * 16 + n] = acc[m][nt][i];
  }
  __syncthreads();

  // ---- LSTM cell + state writes (+ FC fuse for L2) ----
  constexpr int NCELL = (MT * 4 * 32) / 256;  // cells per thread (L2: 4, L1: 2)
  float p6[6] = {0, 0, 0, 0, 0, 0};
#pragma unroll
  for (int i = 0; i < NCELL; ++i) {
    int idx = i * 256 + tid;
    int ch = idx >> 5, pI = idx & 31;
    float zi = zs[(ch * 4 + 0) * ZS + pI];
    float zf = zs[(ch * 4 + 1) * ZS + pI];
    float zo = zs[(ch * 4 + 2) * ZS + pI];
    float zg = zs[(ch * 4 + 3) * ZS + pI];
    int hg = mb * (MT * 4) + ch;
    zi += bias[0 * H + hg];
    zf += bias[1 * H + hg];
    zo += bias[2 * H + hg];
    zg += bias[3 * H + hg];
    int y = Y0 + (pI >> 3), x = X0 + (pI & 7);
    int cidx = hg * 4096 + y * 64 + x;
    float cold = cst[cidx];
    float cn = sigm(zf) * cold + sigm(zi) * tanh_fast(zg);
    float hn = sigm(zo) * tanh_fast(cn);
    cst[cidx] = cn;
    hout[cidx] = hn;
    f16 hh = (f16)hn;
    f16 hl = (f16)(hn - (float)hh);
    int pidx = (y + 1) * 66 + (x + 1);
    d1hi[pidx * D1S + D1O + hg] = f2u(hh);
    d1lo[pidx * D1S + D1O + hg] = f2u(hl);
    if (LAYER == 1) {
      d2hi[pidx * 32 + hg] = f2u(hh);   // in2a: h1, 32-ch stride
      d2lo[pidx * 32 + hg] = f2u(hl);
    } else {
#pragma unroll
      for (int j = 0; j < 6; ++j) p6[j] += hn * fcw[j * 262144 + cidx];
    }
  }

  if (LAYER == 2) {
#pragma unroll
    for (int j = 0; j < 6; ++j)
#pragma unroll
      for (int off = 32; off > 0; off >>= 1) p6[j] += __shfl_xor(p6[j], off, 64);
    if (lane == 0)
#pragma unroll
      for (int j = 0; j < 6; ++j) red[w][j] = p6[j];
    __syncthreads();
    if (tid < 6) atomicAdd(pose_t + tid, red[0][tid] + red[1][tid] + red[2][tid] + red[3][tid]);
  } else {
    // stage x[t+1] into in1 next-parity (c0-2); d1 is in1-next
    if (mb == 0 && tid < 32) {
      int y = Y0 + (tid >> 3), x = X0 + (tid & 7);
      int pidx = (y + 1) * 66 + (x + 1);
#pragma unroll
      for (int c = 0; c < 3; ++c) {
        float v = xn[c * 4096 + y * 64 + x];
        f16 vh = (f16)v;
        f16 vl = (f16)(v - (float)vh);
        d1hi[pidx * 48 + c] = f2u(vh);
        d1lo[pidx * 48 + c] = f2u(vl);
      }
    }
  }
}

// ---- fused temporal-skew kernel: blocks 0-255 = L1[t], 256-511 = L2[t-1] ----
__global__ __launch_bounds__(256, 2) void fused_step(
    int t,
    const ushort_t* __restrict__ i1rhi, const ushort_t* __restrict__ i1rlo,
    ushort_t* __restrict__ i1whi, ushort_t* __restrict__ i1wlo,
    const ushort_t* __restrict__ i2arhi, const ushort_t* __restrict__ i2arlo,
    const ushort_t* __restrict__ i2brhi, const ushort_t* __restrict__ i2brlo,
    ushort_t* __restrict__ i2awhi, ushort_t* __restrict__ i2awlo,
    ushort_t* __restrict__ i2bwhi, ushort_t* __restrict__ i2bwlo,
    const ushort_t* __restrict__ wp1, const ushort_t* __restrict__ wp2,
    const float* __restrict__ b1, const float* __restrict__ b2,
    float* __restrict__ c1o, float* __restrict__ h1o,
    float* __restrict__ c2o, float* __restrict__ h2o,
    const float* __restrict__ fcw, float* __restrict__ pose_t,
    const float* __restrict__ xn) {
  // union'd shared memory: max over both roles (L2 sizes), 41 KB -> 2 blocks/CU
  __shared__ __align__(16) ushort_t Bh[6240];   // max(60*72, 60*104)
  __shared__ __align__(16) ushort_t Bl[6240];
  __shared__ float zs[4224];                    // max(64,128)*33
  __shared__ float red[4][6];

  int bid = blockIdx.x;
  if (bid < 256) {
    if (t >= 128) return;
    conv_body<1>(bid, i1rhi, i1rlo, nullptr, nullptr, wp1, b1, c1o, h1o,
                 i1whi, i1wlo,          // h1 -> in1 next @c3 (+ x[t+1] @c0-2)
                 i2awhi, i2awlo,        // h1 -> in2a[t&1]
                 nullptr, nullptr, xn, Bh, Bl, zs, red);
  } else {
    if (t < 1) return;
    conv_body<2>(bid - 256, i2arhi, i2arlo, i2brhi, i2brlo, wp2, b2, c2o, h2o,
                 i2bwhi, i2bwlo,        // h2 -> in2b[t&1]
                 nullptr, nullptr,
                 fcw, pose_t, nullptr, Bh, Bl, zs, red);
  }
}

extern "C" void kernel_launch(void* const* d_in, const int* in_sizes, int n_in, void* d_out,
                              int out_size, void* d_ws, size_t ws_size, hipStream_t stream) {
  const float* input = (const float*)d_in[0];
  const float* w1 = (const float*)d_in[1];
  const float* b1 = (const float*)d_in[2];
  const float* w2 = (const float*)d_in[3];
  const float* b2 = (const float*)d_in[4];
  const float* fcw = (const float*)d_in[5];
  const float* fcb = (const float*)d_in[6];

  float* out = (float*)d_out;
  float* pose = out;
  float* h1o = out + 768;
  float* c1o = h1o + 131072;
  float* h2o = c1o + 131072;
  float* c2o = h2o + 262144;

  ushort_t* ws = (ushort_t*)d_ws;
  ushort_t* in1hi[2] = {ws, ws + IN1SZ};
  ushort_t* in1lo[2] = {ws + 2 * IN1SZ, ws + 3 * IN1SZ};
  ushort_t* ab = ws + 4 * IN1SZ;
  ushort_t* i2ahi[2] = {ab, ab + IN2ASZ};
  ushort_t* i2alo[2] = {ab + 2 * IN2ASZ, ab + 3 * IN2ASZ};
  ushort_t* bb = ab + 4 * IN2ASZ;
  ushort_t* i2bhi[2] = {bb, bb + IN2BSZ};
  ushort_t* i2blo[2] = {bb + 2 * IN2BSZ, bb + 3 * IN2BSZ};
  ushort_t* wp1 = ws + WP1OFF;
  ushort_t* wp2 = ws + WP2OFF;

  // zero state buffers (t=0 h-states + padded borders + c-pads), c/h fp32 states
  hipMemsetAsync(ws, 0, (size_t)WP1OFF * 2, stream);
  hipMemsetAsync(out + 768, 0, (size_t)786432 * 4, stream);
  pack_kernel<<<339, 256, 0, stream>>>(w1, w2, fcb, input, pose, wp1, wp2, in1hi[0], in1lo[0]);

  // K_t: L1[t] (t<128) + L2[t-1] (t>=1).
  //   L1[t]: reads in1[t&1]; writes in1[(t+1)&1] (h1@c3 + x[t+1]@c0) and in2a[t&1].
  //   L2[t-1]: reads in2a/in2b[(t-1)&1]; writes in2b[t&1].
  for (int t = 0; t <= 128; ++t) {
    int p = t & 1, pn = p ^ 1;
    int tn = (t + 1 < 128) ? t + 1 : 127;
    float* pose_t = pose + ((t > 0) ? (t - 1) * 6 : 0);
    fused_step<<<512, 256, 0, stream>>>(
        t,
        in1hi[p], in1lo[p], in1hi[pn], in1lo[pn],
        i2ahi[pn], i2alo[pn], i2bhi[pn], i2blo[pn],   // (t-1)&1 == pn
        i2ahi[p], i2alo[p], i2bhi[p], i2blo[p],
        wp1, wp2, b1, b2, c1o, h1o, c2o, h2o,
        fcw, pose_t,
        input + (size_t)tn * 12288);
  }
}